// Round 1
// baseline (448.883 us; speedup 1.0000x reference)
//
#include <hip/hip_runtime.h>
#include <math.h>

#define NN 4096
#define NB 4
#define KSPLIT 4
#define NITER 10

// ---------------- per-(b,n) stats: a = exp(-|f|^2/2), u = f/|f| ----------------
__global__ __launch_bounds__(256) void stats_kernel(const float* __restrict__ dp,
    float* __restrict__ a, float* __restrict__ ux, float* __restrict__ uy) {
    int i = blockIdx.x * 256 + threadIdx.x;           // 0..16383  (b*NN + n)
    float x = dp[2 * i], y = dp[2 * i + 1];
    float sq = x * x + y * y;
    a[i] = expf(-0.5f * sq);
    float inv = 1.0f / sqrtf(sq);
    ux[i] = x * inv;
    uy[i] = y * inv;
}

// ---------------- W_sym = (W + W^T)/2, LDS-tiled transpose ----------------
__global__ __launch_bounds__(256) void wsym_kernel(const float* __restrict__ W,
                                                   float* __restrict__ S) {
    __shared__ float tile[64][65];
    int bi = blockIdx.y, bj = blockIdx.x;
    int tx = threadIdx.x & 63, ty = threadIdx.x >> 6;
#pragma unroll
    for (int i = 0; i < 16; ++i) {
        int r = ty + i * 4;
        tile[r][tx] = W[(size_t)(bj * 64 + r) * NN + bi * 64 + tx];
    }
    __syncthreads();
#pragma unroll
    for (int i = 0; i < 16; ++i) {
        int r = ty + i * 4;
        size_t n = bi * 64 + r, m = bj * 64 + tx;
        S[n * NN + m] = 0.5f * (W[n * NN + m] + tile[tx][r]);  // tile[tx][r] == W[m][n]
    }
}

// ---------------- Ypart[slab][n][c] = sum_{m in slab} M[n][m] * T[m][c] ----------------
// block: 256 thr = 4 waves; wave: 4 groups of 16 lanes; group handles 2 rows.
// lanes with same s (different g) read the same T words -> coalesced/broadcast.
__global__ __launch_bounds__(256) void matvec_kernel(const float* __restrict__ M,
    const float* __restrict__ T, float* __restrict__ Ypart) {
    const int lane = threadIdx.x & 63;
    const int wid  = threadIdx.x >> 6;
    const int g = lane >> 4, s = lane & 15;
    const int row0  = blockIdx.x * 32 + wid * 8 + g * 2;
    const int mbase = blockIdx.y * 1024;

    float acc0[12], acc1[12];
#pragma unroll
    for (int c = 0; c < 12; ++c) { acc0[c] = 0.f; acc1[c] = 0.f; }

    const float* Mr0 = M + (size_t)row0 * NN;
    const float* Mr1 = M + (size_t)(row0 + 1) * NN;

#pragma unroll 4
    for (int ch = 0; ch < 16; ++ch) {
        int m = mbase + ch * 64 + s * 4;
        float4 wa = *(const float4*)(Mr0 + m);
        float4 wb = *(const float4*)(Mr1 + m);
        float wv0[4] = {wa.x, wa.y, wa.z, wa.w};
        float wv1[4] = {wb.x, wb.y, wb.z, wb.w};
#pragma unroll
        for (int j = 0; j < 4; ++j) {
            const float4* tp = (const float4*)(T + (size_t)(m + j) * 12);
            float4 ta = tp[0], tb = tp[1], tc = tp[2];
            float tv[12] = {ta.x, ta.y, ta.z, ta.w, tb.x, tb.y, tb.z, tb.w,
                            tc.x, tc.y, tc.z, tc.w};
#pragma unroll
            for (int c = 0; c < 12; ++c) acc0[c] += wv0[j] * tv[c];
#pragma unroll
            for (int c = 0; c < 12; ++c) acc1[c] += wv1[j] * tv[c];
        }
    }
    // reduce across the 16 lanes of this group (xor masks stay within group)
#pragma unroll
    for (int mask = 1; mask < 16; mask <<= 1) {
#pragma unroll
        for (int c = 0; c < 12; ++c) {
            acc0[c] += __shfl_xor(acc0[c], mask, 64);
            acc1[c] += __shfl_xor(acc1[c], mask, 64);
        }
    }
    if (s == 0) {
        float* y0 = Ypart + ((size_t)blockIdx.y * NN + row0) * 12;
        *(float4*)(y0 + 0) = make_float4(acc0[0], acc0[1], acc0[2], acc0[3]);
        *(float4*)(y0 + 4) = make_float4(acc0[4], acc0[5], acc0[6], acc0[7]);
        *(float4*)(y0 + 8) = make_float4(acc0[8], acc0[9], acc0[10], acc0[11]);
        float* y1 = y0 + 12;
        *(float4*)(y1 + 0) = make_float4(acc1[0], acc1[1], acc1[2], acc1[3]);
        *(float4*)(y1 + 4) = make_float4(acc1[4], acc1[5], acc1[6], acc1[7]);
        *(float4*)(y1 + 8) = make_float4(acc1[8], acc1[9], acc1[10], acc1[11]);
    }
}

// ---------------- fallback: Z[m][c] += sum_n W[n][m] * T[n][c] (atomics) ----------------
__global__ __launch_bounds__(256) void colmv_kernel(const float* __restrict__ M,
    const float* __restrict__ T, float* __restrict__ Z) {
    int m = blockIdx.x * 256 + threadIdx.x;
    int n0 = blockIdx.y * 512;
    float acc[12];
#pragma unroll
    for (int c = 0; c < 12; ++c) acc[c] = 0.f;
    for (int n = n0; n < n0 + 512; ++n) {
        float w = M[(size_t)n * NN + m];
        const float* t = T + (size_t)n * 12;
#pragma unroll
        for (int c = 0; c < 12; ++c) acc[c] += w * t[c];
    }
#pragma unroll
    for (int c = 0; c < 12; ++c) atomicAdd(&Z[(size_t)m * 12 + c], acc[c]);
}

// ---------------- finalize previous iteration + build T for next ----------------
__global__ __launch_bounds__(256) void update_kernel(const float* __restrict__ logits,
    const float* __restrict__ a, const float* __restrict__ ux, const float* __restrict__ uy,
    const float* __restrict__ Ypart, const float* __restrict__ Z,
    float* __restrict__ T, float* __restrict__ lout) {
    int m = blockIdx.x * 256 + threadIdx.x;   // 0..4095
#pragma unroll
    for (int b = 0; b < NB; ++b) {
        int idx = b * NN + m;
        float l = logits[idx];
        float av = a[idx], uxv = ux[idx], uyv = uy[idx];
        if (Ypart) {
            float s0 = 0.f, s1 = 0.f, s2 = 0.f;
#pragma unroll
            for (int sl = 0; sl < KSPLIT; ++sl) {
                const float* yp = Ypart + ((size_t)sl * NN + m) * 12 + b * 3;
                s0 += yp[0]; s1 += yp[1]; s2 += yp[2];
            }
            if (Z) {
                const float* zp = Z + (size_t)m * 12 + b * 3;
                s0 = 0.5f * (s0 + zp[0]);
                s1 = 0.5f * (s1 + zp[1]);
                s2 = 0.5f * (s2 + zp[2]);
            }
            l += av * (s0 - uxv * s1 - uyv * s2);
        }
        if (lout) lout[idx] = l;
        if (T) {
            float mv = 2.0f / (1.0f + expf(-l)) - 1.0f;
            float t0 = av * mv;
            T[(size_t)m * 12 + b * 3 + 0] = t0;
            T[(size_t)m * 12 + b * 3 + 1] = t0 * uxv;
            T[(size_t)m * 12 + b * 3 + 2] = t0 * uyv;
        }
    }
}

extern "C" void kernel_launch(void* const* d_in, const int* in_sizes, int n_in,
                              void* d_out, int out_size, void* d_ws, size_t ws_size,
                              hipStream_t stream) {
    const float* delta_p = (const float*)d_in[0];   // (4,64,64,2)
    const float* logits  = (const float*)d_in[1];   // (4,4096,1)
    const float* W       = (const float*)d_in[2];   // (1,4096,4096)
    float* out = (float*)d_out;
    char* ws = (char*)d_ws;

    const size_t wsym_bytes  = (size_t)NN * NN * 4;        // 64 MiB
    const size_t stats_bytes = 3 * (size_t)NB * NN * 4;    // 192 KiB
    const size_t T_bytes     = (size_t)NN * 12 * 4;        // 192 KiB
    const size_t Yp_bytes    = (size_t)KSPLIT * NN * 12 * 4;
    const size_t Z_bytes     = T_bytes;

    bool big = ws_size >= wsym_bytes + stats_bytes + T_bytes + Yp_bytes;

    float *Wsym = nullptr, *A, *Ux, *Uy, *T, *Yp, *Z = nullptr;
    if (big) {
        Wsym = (float*)ws;
        A  = (float*)(ws + wsym_bytes);
        T  = (float*)(ws + wsym_bytes + stats_bytes);
        Yp = (float*)(ws + wsym_bytes + stats_bytes + T_bytes);
    } else {
        if (ws_size < stats_bytes + T_bytes + Yp_bytes + Z_bytes) return;  // cannot run
        A  = (float*)ws;
        T  = (float*)(ws + stats_bytes);
        Yp = (float*)(ws + stats_bytes + T_bytes);
        Z  = (float*)(ws + stats_bytes + T_bytes + Yp_bytes);
    }
    Ux = A + NB * NN;
    Uy = A + 2 * NB * NN;

    stats_kernel<<<64, 256, 0, stream>>>(delta_p, A, Ux, Uy);

    const float* M;
    if (big) {
        wsym_kernel<<<dim3(64, 64), 256, 0, stream>>>(W, Wsym);
        M = Wsym;
    } else {
        M = W;
    }

    for (int it = 0; it < NITER; ++it) {
        update_kernel<<<16, 256, 0, stream>>>(logits, A, Ux, Uy,
            it == 0 ? nullptr : Yp, it == 0 ? nullptr : Z, T, nullptr);
        if (!big) {
            hipMemsetAsync(Z, 0, Z_bytes, stream);
            colmv_kernel<<<dim3(16, 8), 256, 0, stream>>>(M, T, Z);
        }
        matvec_kernel<<<dim3(128, KSPLIT), 256, 0, stream>>>(M, T, Yp);
    }
    update_kernel<<<16, 256, 0, stream>>>(logits, A, Ux, Uy, Yp, Z, nullptr, out);
}

// Round 3
// 251.728 us; speedup vs baseline: 1.7832x; 1.7832x over previous
//
#include <hip/hip_runtime.h>
#include <math.h>

#define NN 4096
#define NB 4
#define MSPLIT 16
#define MSLAB 256          // NN / MSPLIT
#define NITER 10

// persistent scratch in module .bss (no ws-size assumptions needed)
__device__ __align__(16) float gA [NB * NN];
__device__ __align__(16) float gUx[NB * NN];
__device__ __align__(16) float gUy[NB * NN];
__device__ __align__(16) float gYp[2][(size_t)MSPLIT * NN * 12];

// ---------------- per-(b,n) stats: a = exp(-|f|^2/2), u = f/|f| ----------------
__global__ __launch_bounds__(256) void stats_kernel(const float* __restrict__ dp) {
    int i = blockIdx.x * 256 + threadIdx.x;          // 0..16383
    float x = dp[2 * i], y = dp[2 * i + 1];
    float sq = x * x + y * y;
    gA[i] = expf(-0.5f * sq);
    float inv = 1.0f / sqrtf(sq);
    gUx[i] = x * inv;
    gUy[i] = y * inv;
}

// ---------------- W_sym = (W + W^T)/2 : triangular pair blocks ----------------
__global__ __launch_bounds__(256) void wsym_kernel(const float* __restrict__ W,
                                                   float* __restrict__ S) {
    __shared__ float At[64][65];
    __shared__ float Bt[64][65];
    int idx = blockIdx.x, bi = 0, rem = 64;
    while (idx >= rem) { idx -= rem; ++bi; --rem; }
    int bj = bi + idx;
    int tx = threadIdx.x & 63, ty = threadIdx.x >> 6;
#pragma unroll
    for (int i = 0; i < 16; ++i) {
        int r = ty + i * 4;
        At[r][tx] = W[(size_t)(bi * 64 + r) * NN + bj * 64 + tx];
        Bt[r][tx] = W[(size_t)(bj * 64 + r) * NN + bi * 64 + tx];
    }
    __syncthreads();
#pragma unroll
    for (int i = 0; i < 16; ++i) {
        int r = ty + i * 4;
        S[(size_t)(bi * 64 + r) * NN + bj * 64 + tx] = 0.5f * (At[r][tx] + Bt[tx][r]);
        S[(size_t)(bj * 64 + r) * NN + bi * 64 + tx] = 0.5f * (Bt[r][tx] + At[tx][r]);
    }
}

// ---------------- fused: build T-slab in LDS, then Y[slab] partial matvec -------
// grid (64 rowblocks, 16 mslabs), 256 thr. Wave: 4 groups x 16 lanes; group owns
// 4 rows; 16 lanes split m (stride-4 float4). T in 3 swizzled f4 planes.
__global__ __launch_bounds__(256, 4) void matvec_kernel(const float* __restrict__ M,
    const float* __restrict__ logits, int rd, int first) {
    __shared__ float4 Tp[3][MSLAB];                  // 12 KB
    __shared__ __align__(16) float red[64 * 4 * 12]; // 12 KB

    const int tid = threadIdx.x;
    const int mb = blockIdx.y * MSLAB;
    const float* __restrict__ Yprev = gYp[rd];
    float* __restrict__ Ynext = gYp[rd ^ 1];

    // ---- prologue: T values for this slab's 256 m (one per thread) ----
    {
        int m = mb + tid;
        float S12[12];
#pragma unroll
        for (int c = 0; c < 12; ++c) S12[c] = 0.f;
        if (!first) {
#pragma unroll 4
            for (int sl = 0; sl < MSPLIT; ++sl) {
                const float4* p = (const float4*)(Yprev + ((size_t)sl * NN + m) * 12);
                float4 x = p[0], y = p[1], z = p[2];
                S12[0] += x.x; S12[1] += x.y; S12[2]  += x.z; S12[3]  += x.w;
                S12[4] += y.x; S12[5] += y.y; S12[6]  += y.z; S12[7]  += y.w;
                S12[8] += z.x; S12[9] += z.y; S12[10] += z.z; S12[11] += z.w;
            }
        }
        float vals[12];
#pragma unroll
        for (int b = 0; b < NB; ++b) {
            int idx = b * NN + m;
            float av = gA[idx], uxv = gUx[idx], uyv = gUy[idx];
            float l = logits[idx];
            if (!first) l += av * (S12[b * 3] - uxv * S12[b * 3 + 1] - uyv * S12[b * 3 + 2]);
            float mv = 2.0f / (1.0f + expf(-l)) - 1.0f;
            float t0 = av * mv;
            vals[b * 3] = t0; vals[b * 3 + 1] = t0 * uxv; vals[b * 3 + 2] = t0 * uyv;
        }
        int sm = tid ^ ((tid >> 3) & 7);             // bank-group swizzle
        Tp[0][sm] = make_float4(vals[0], vals[1], vals[2],  vals[3]);
        Tp[1][sm] = make_float4(vals[4], vals[5], vals[6],  vals[7]);
        Tp[2][sm] = make_float4(vals[8], vals[9], vals[10], vals[11]);
    }
    __syncthreads();

    // ---- main accumulation ----
    const int lane = tid & 63, wid = tid >> 6;
    const int g = lane >> 4, s = lane & 15;
    const int row0 = blockIdx.x * 64 + wid * 16 + g * 4;
    const float* Mr = M + (size_t)row0 * NN + mb;

    float acc[4][12];
#pragma unroll
    for (int r = 0; r < 4; ++r)
#pragma unroll
        for (int c = 0; c < 12; ++c) acc[r][c] = 0.f;

#pragma unroll 2
    for (int ch = 0; ch < MSLAB / 64; ++ch) {
        int ml = ch * 64 + s * 4;
        float4 w4[4];
#pragma unroll
        for (int r = 0; r < 4; ++r) w4[r] = *(const float4*)(Mr + (size_t)r * NN + ml);
        float wv[4][4];
#pragma unroll
        for (int r = 0; r < 4; ++r) {
            wv[r][0] = w4[r].x; wv[r][1] = w4[r].y; wv[r][2] = w4[r].z; wv[r][3] = w4[r].w;
        }
#pragma unroll
        for (int j = 0; j < 4; ++j) {
            int mj = ml + j;
            int sm = mj ^ ((mj >> 3) & 7);
            float4 t0 = Tp[0][sm], t1 = Tp[1][sm], t2 = Tp[2][sm];
            float tv[12] = {t0.x, t0.y, t0.z, t0.w, t1.x, t1.y, t1.z, t1.w,
                            t2.x, t2.y, t2.z, t2.w};
#pragma unroll
            for (int r = 0; r < 4; ++r)
#pragma unroll
                for (int c = 0; c < 12; ++c) acc[r][c] += wv[r][j] * tv[c];
        }
    }

    // ---- reduce: 2 xor-shuffle steps, then 4-way via LDS ----
#pragma unroll
    for (int mask = 1; mask <= 2; mask <<= 1)
#pragma unroll
        for (int r = 0; r < 4; ++r)
#pragma unroll
            for (int c = 0; c < 12; ++c) acc[r][c] += __shfl_xor(acc[r][c], mask, 64);

    if ((s & 3) == 0) {
        int sub = s >> 2;
#pragma unroll
        for (int r = 0; r < 4; ++r) {
            int rl = wid * 16 + g * 4 + r;
            float4* dst = (float4*)&red[(rl * 4 + sub) * 12];
            dst[0] = make_float4(acc[r][0], acc[r][1], acc[r][2],  acc[r][3]);
            dst[1] = make_float4(acc[r][4], acc[r][5], acc[r][6],  acc[r][7]);
            dst[2] = make_float4(acc[r][8], acc[r][9], acc[r][10], acc[r][11]);
        }
    }
    __syncthreads();

    {
        int rl = tid >> 2, c0 = (tid & 3) * 3;
        float s0 = 0.f, s1 = 0.f, s2 = 0.f;
#pragma unroll
        for (int sub = 0; sub < 4; ++sub) {
            const float* p = &red[(rl * 4 + sub) * 12 + c0];
            s0 += p[0]; s1 += p[1]; s2 += p[2];
        }
        int row = blockIdx.x * 64 + rl;
        float* dst = Ynext + ((size_t)blockIdx.y * NN + row) * 12 + c0;
        dst[0] = s0; dst[1] = s1; dst[2] = s2;
    }
}

// ---------------- final: l = logits + a*(S0 - ux*S1 - uy*S2) -> out ----------------
__global__ __launch_bounds__(256) void final_kernel(const float* __restrict__ logits,
                                                    int rd, float* __restrict__ out) {
    int m = blockIdx.x * 256 + threadIdx.x;          // 0..4095
    const float* __restrict__ Y = gYp[rd];
    float S12[12];
#pragma unroll
    for (int c = 0; c < 12; ++c) S12[c] = 0.f;
#pragma unroll 4
    for (int sl = 0; sl < MSPLIT; ++sl) {
        const float4* p = (const float4*)(Y + ((size_t)sl * NN + m) * 12);
        float4 x = p[0], y = p[1], z = p[2];
        S12[0] += x.x; S12[1] += x.y; S12[2]  += x.z; S12[3]  += x.w;
        S12[4] += y.x; S12[5] += y.y; S12[6]  += y.z; S12[7]  += y.w;
        S12[8] += z.x; S12[9] += z.y; S12[10] += z.z; S12[11] += z.w;
    }
#pragma unroll
    for (int b = 0; b < NB; ++b) {
        int idx = b * NN + m;
        out[idx] = logits[idx] +
                   gA[idx] * (S12[b * 3] - gUx[idx] * S12[b * 3 + 1] - gUy[idx] * S12[b * 3 + 2]);
    }
}

extern "C" void kernel_launch(void* const* d_in, const int* in_sizes, int n_in,
                              void* d_out, int out_size, void* d_ws, size_t ws_size,
                              hipStream_t stream) {
    const float* delta_p = (const float*)d_in[0];   // (4,64,64,2)
    const float* logits  = (const float*)d_in[1];   // (4,4096,1)
    const float* W       = (const float*)d_in[2];   // (1,4096,4096)
    float* out = (float*)d_out;

    float* Wsym = (float*)d_ws;                      // 64 MiB (ws >= 65 MiB observed)

    stats_kernel<<<64, 256, 0, stream>>>(delta_p);
    wsym_kernel<<<2080, 256, 0, stream>>>(W, Wsym);  // 64*65/2 triangular tile pairs

    for (int it = 0; it < NITER; ++it) {
        int rd = it & 1;                             // it=0 writes gYp[1]; it=9 writes gYp[0]
        matvec_kernel<<<dim3(64, MSPLIT), 256, 0, stream>>>(Wsym, logits, rd, it == 0 ? 1 : 0);
    }
    final_kernel<<<16, 256, 0, stream>>>(logits, 0, out);
}